// Round 10
// baseline (173.734 us; speedup 1.0000x reference)
//
#include <hip/hip_runtime.h>

#define NN 2048
#define NH 4
#define DD 64
#define FIN 128
#define NB 4
#define LOG2E 1.44269504f

typedef unsigned short u16;
typedef unsigned int u32;
typedef short sh8 __attribute__((ext_vector_type(8)));
typedef float f32x4 __attribute__((ext_vector_type(4)));

static __device__ __forceinline__ u16 f2bf(float f) {   // RNE
    u32 u = __builtin_bit_cast(u32, f);
    u += 0x7fffu + ((u >> 16) & 1u);
    return (u16)(u >> 16);
}
static __device__ __forceinline__ u32 pk_bf(float a, float b) {
    u32 ua = __builtin_bit_cast(u32, a) + 0x8000u;
    u32 ub = __builtin_bit_cast(u32, b) + 0x8000u;
    return __builtin_amdgcn_perm(ub, ua, 0x07060302u);
}
static __device__ __forceinline__ float fast_exp2(float x) {
    float r;
    asm("v_exp_f32 %0, %1" : "=v"(r) : "v"(x));
    return r;
}

// ---- runtime C/D layout probe (load-bearing since R4) ----
static __device__ __forceinline__ void cd_probe(int ln15, int q, int* irow, int* icol) {
    sh8 pa, pb, qa, qb;
    #pragma unroll
    for (int ii = 0; ii < 8; ++ii) {
        pa[ii] = (short)f2bf((float)ln15);   // A[m][k] = m
        pb[ii] = 0;
        qa[ii] = 0;
        qb[ii] = (short)f2bf((float)ln15);   // B[k][n] = n
    }
    if (q == 0) { pb[0] = (short)f2bf(1.0f); qa[0] = (short)f2bf(1.0f); }
    f32x4 z = {};
    f32x4 prow = __builtin_amdgcn_mfma_f32_16x16x32_bf16(pa, pb, z, 0, 0, 0);
    f32x4 pcol = __builtin_amdgcn_mfma_f32_16x16x32_bf16(qa, qb, z, 0, 0, 0);
    #pragma unroll
    for (int r = 0; r < 4; ++r) {
        irow[r] = (int)(prow[r] + 0.5f);
        icol[r] = (int)(pcol[r] + 0.5f);
    }
}

// ws layout (bytes):
//   hTf  fragment-major  @ 0        : 4194304  ([b][hd][j32][dt4][lane64][8] bf16)
//   ei   [B][H][N] f32   @ 4194304  : 131072   (log2e-scaled)
//   ej   [B][H][N] f32   @ 4325376  : 131072   (log2e-scaled)

// h = x@W in MFMA fragment-major layout + ei/ej. grid (nb=64, b=4), block 256, wave = head.
__global__ __launch_bounds__(256)
void k_gemm_h(const float* __restrict__ x, const float* __restrict__ W,
              const float* __restrict__ a,
              u16* __restrict__ hTf, float* __restrict__ ei_g, float* __restrict__ ej_g) {
    const int nb = blockIdx.x, b = blockIdx.y;
    const int tid = threadIdx.x, hd = tid >> 6, lane = tid & 63, ln15 = lane & 15, q = lane >> 4;
    const int q8 = q * 8;
    const int n0 = nb * 32;

    __shared__ u16 WTs[256][136];          // [c][k] bf16, 16B-aligned rows
    __shared__ u16 xs[32][136];
    __shared__ float cs[NH][2][16][20];    // per-wave canonicalization buffer

    {   // transpose W (f32 [128][256]) -> WTs bf16 [c][k]
        const int c = tid;
        #pragma unroll 8
        for (int k = 0; k < FIN; ++k)
            WTs[c][k] = f2bf(W[(size_t)k * 256 + c]);
    }
    {   // stage x rows n0..n0+31 as bf16
        const int col = (tid & 31) * 4;
        const int r0  = tid >> 5;
        #pragma unroll
        for (int rr = 0; rr < 4; ++rr) {
            const int row = r0 + rr * 8;
            const float4 v = *(const float4*)(x + ((size_t)(b * NN + n0 + row)) * FIN + col);
            *(u32*)&xs[row][col]     = pk_bf(v.x, v.y);
            *(u32*)&xs[row][col + 2] = pk_bf(v.z, v.w);
        }
    }
    __syncthreads();

    int irow[4], icol[4];
    cd_probe(ln15, q, irow, icol);

    f32x4 acc[4][2] = {};                  // [ct][nt]
    #pragma unroll
    for (int ks = 0; ks < 4; ++ks) {
        sh8 af[4], bfr[2];
        #pragma unroll
        for (int ct = 0; ct < 4; ++ct)
            af[ct] = *(const sh8*)&WTs[hd * 64 + ct * 16 + ln15][ks * 32 + q8];
        #pragma unroll
        for (int nt = 0; nt < 2; ++nt)
            bfr[nt] = *(const sh8*)&xs[nt * 16 + ln15][ks * 32 + q8];
        #pragma unroll
        for (int ct = 0; ct < 4; ++ct)
            #pragma unroll
            for (int nt = 0; nt < 2; ++nt)
                acc[ct][nt] = __builtin_amdgcn_mfma_f32_16x16x32_bf16(af[ct], bfr[nt], acc[ct][nt], 0, 0, 0);
    }

    float eip[2] = {}, ejq[2] = {};
    #pragma unroll
    for (int ct = 0; ct < 4; ++ct) {
        #pragma unroll
        for (int nt = 0; nt < 2; ++nt)
            #pragma unroll
            for (int r = 0; r < 4; ++r)
                cs[hd][nt][irow[r]][icol[r]] = acc[ct][nt][r];

        // fragment-major write: lane (ln15,q) holds d=ct*16+ln15, j=n0+8q+i
        {
            const float4 c0 = *(const float4*)&cs[hd][q >> 1][ln15][(q & 1) * 8];
            const float4 c1 = *(const float4*)&cs[hd][q >> 1][ln15][(q & 1) * 8 + 4];
            uint4 o;
            o.x = pk_bf(c0.x, c0.y); o.y = pk_bf(c0.z, c0.w);
            o.z = pk_bf(c1.x, c1.y); o.w = pk_bf(c1.z, c1.w);
            *(uint4*)(hTf + ((((size_t)(b * NH + hd) * 64 + nb) * 4 + ct) * 512) + lane * 8) = o;
        }

        float a1v[4], a2v[4];
        #pragma unroll
        for (int r = 0; r < 4; ++r) {
            const int d = ct * 16 + 4 * q + r;
            a1v[r] = a[d] * LOG2E;
            a2v[r] = a[64 + d] * LOG2E;
        }
        #pragma unroll
        for (int nt = 0; nt < 2; ++nt)
            #pragma unroll
            for (int r = 0; r < 4; ++r) {
                const float v = cs[hd][nt][4 * q + r][ln15];
                eip[nt] += v * a1v[r];
                ejq[nt] += v * a2v[r];
            }
    }
    #pragma unroll
    for (int nt = 0; nt < 2; ++nt) {
        eip[nt] += __shfl_xor(eip[nt], 16);
        eip[nt] += __shfl_xor(eip[nt], 32);
        ejq[nt] += __shfl_xor(ejq[nt], 16);
        ejq[nt] += __shfl_xor(ejq[nt], 32);
    }
    if (lane < 16) {
        const size_t bhd = (size_t)(b * NH + hd) * NN;
        #pragma unroll
        for (int nt = 0; nt < 2; ++nt) {
            ei_g[bhd + n0 + nt * 16 + lane] = eip[nt];
            ej_g[bhd + n0 + nt * 16 + lane] = ejq[nt];
        }
    }
}

// Fused attention: grid (ib=64, b=4), block 256 (wave = head), i-tile 32, all j in-block.
// Prologue: adj slice -> LDS bitmask (each adj elem read once chip-wide).
// Epilogue: normalize + head-mean -> out. No partials, no combine.
__global__ __launch_bounds__(256, 1)
void k_attn(const int* __restrict__ adj, const u16* __restrict__ hTf,
            const float* __restrict__ ei_g, const float* __restrict__ ej_g,
            float* __restrict__ out) {
    const int ib = blockIdx.x, b = blockIdx.y;
    const int tid = threadIdx.x, hd = tid >> 6, lane = tid & 63, ln15 = lane & 15, q = lane >> 4;
    const int q8 = q * 8;
    const int i0 = ib * 32;

    __shared__ u32 msk_s[64][32];          // [j32][i]
    __shared__ float o_s[NH][32][68];      // +4 pad (keeps 16B align, spreads banks)
    __shared__ float l_s[NH][32];

    // ---- prologue: build bitmask in LDS; wave hd handles rows hd*8..hd*8+7 ----
    #pragma unroll
    for (int rr = 0; rr < 8; ++rr) {
        const int i = hd * 8 + rr;
        #pragma unroll
        for (int c256 = 0; c256 < 8; ++c256) {
            const int4 v = *(const int4*)(adj + ((size_t)(b * NN + i0 + i)) * NN + c256 * 256 + lane * 4);
            u32 nib = (v.x ? 1u : 0u) | (v.y ? 2u : 0u) | (v.z ? 4u : 0u) | (v.w ? 8u : 0u);
            u32 w = nib << (4 * (lane & 7));
            w |= __shfl_xor(w, 1);
            w |= __shfl_xor(w, 2);
            w |= __shfl_xor(w, 4);
            if ((lane & 7) == 0) msk_s[c256 * 8 + (lane >> 3)][i] = w;
        }
    }

    int irow[4], icol[4];
    cd_probe(ln15, q, irow, icol);
    __syncthreads();

    const size_t bhd = (size_t)(b * NH + hd) * NN;
    const float eivA = ei_g[bhd + i0 + ln15];
    const float eivB = ei_g[bhd + i0 + 16 + ln15];
    const float* ejp = ej_g + bhd + q8;
    const u16*   hfp = hTf + (size_t)(b * NH + hd) * (64 * 2048) + (size_t)lane * 8;

    sh8 ones;
    #pragma unroll
    for (int ii = 0; ii < 8; ++ii) ones[ii] = (short)0x3F80;

    f32x4 acc[8] = {};
    f32x4 accl[2] = {};

    float4 e0 = *(const float4*)(ejp);
    float4 e1 = *(const float4*)(ejp + 4);
    sh8 h0 = *(const sh8*)(hfp);
    sh8 h1 = *(const sh8*)(hfp + 512);
    sh8 h2 = *(const sh8*)(hfp + 1024);
    sh8 h3 = *(const sh8*)(hfp + 1536);

    for (int t = 0; t < 64; ++t) {
        const int tn = (t + 1) & 63;                      // wraps; last discarded
        const float4 e0n = *(const float4*)(ejp + tn * 32);
        const float4 e1n = *(const float4*)(ejp + tn * 32 + 4);
        const sh8 h0n = *(const sh8*)(hfp + (size_t)tn * 2048);
        const sh8 h1n = *(const sh8*)(hfp + (size_t)tn * 2048 + 512);
        const sh8 h2n = *(const sh8*)(hfp + (size_t)tn * 2048 + 1024);
        const sh8 h3n = *(const sh8*)(hfp + (size_t)tn * 2048 + 1536);

        const u32 mqA = msk_s[t][ln15] >> q8;
        const u32 mqB = msk_s[t][ln15 + 16] >> q8;
        const float ef[8] = { e0.x, e0.y, e0.z, e0.w, e1.x, e1.y, e1.z, e1.w };
        float pA[8], pB[8];
        #pragma unroll
        for (int ii = 0; ii < 8; ++ii) {
            float eA = eivA + ef[ii];
            float eB = eivB + ef[ii];
            eA = fmaxf(eA, 0.2f * eA);
            eB = fmaxf(eB, 0.2f * eB);
            const float xA = fast_exp2(eA);
            const float xB = fast_exp2(eB);
            pA[ii] = (mqA & (1u << ii)) ? xA : 0.f;
            pB[ii] = (mqB & (1u << ii)) ? xB : 0.f;
        }
        union { uint4 u; sh8 v; } avA, avB;
        avA.u.x = pk_bf(pA[0], pA[1]); avA.u.y = pk_bf(pA[2], pA[3]);
        avA.u.z = pk_bf(pA[4], pA[5]); avA.u.w = pk_bf(pA[6], pA[7]);
        avB.u.x = pk_bf(pB[0], pB[1]); avB.u.y = pk_bf(pB[2], pB[3]);
        avB.u.z = pk_bf(pB[4], pB[5]); avB.u.w = pk_bf(pB[6], pB[7]);

        acc[0] = __builtin_amdgcn_mfma_f32_16x16x32_bf16(avA.v, h0, acc[0], 0, 0, 0);
        acc[1] = __builtin_amdgcn_mfma_f32_16x16x32_bf16(avA.v, h1, acc[1], 0, 0, 0);
        acc[2] = __builtin_amdgcn_mfma_f32_16x16x32_bf16(avA.v, h2, acc[2], 0, 0, 0);
        acc[3] = __builtin_amdgcn_mfma_f32_16x16x32_bf16(avA.v, h3, acc[3], 0, 0, 0);
        accl[0] = __builtin_amdgcn_mfma_f32_16x16x32_bf16(avA.v, ones, accl[0], 0, 0, 0);
        acc[4] = __builtin_amdgcn_mfma_f32_16x16x32_bf16(avB.v, h0, acc[4], 0, 0, 0);
        acc[5] = __builtin_amdgcn_mfma_f32_16x16x32_bf16(avB.v, h1, acc[5], 0, 0, 0);
        acc[6] = __builtin_amdgcn_mfma_f32_16x16x32_bf16(avB.v, h2, acc[6], 0, 0, 0);
        acc[7] = __builtin_amdgcn_mfma_f32_16x16x32_bf16(avB.v, h3, acc[7], 0, 0, 0);
        accl[1] = __builtin_amdgcn_mfma_f32_16x16x32_bf16(avB.v, ones, accl[1], 0, 0, 0);

        e0 = e0n; e1 = e1n;
        h0 = h0n; h1 = h1n; h2 = h2n; h3 = h3n;
    }

    // ---- epilogue: probe-mapped scatter to LDS, then normalize + head-mean ----
    #pragma unroll
    for (int r = 0; r < 4; ++r) {
        l_s[hd][irow[r]]      = accl[0][r];
        l_s[hd][16 + irow[r]] = accl[1][r];
    }
    #pragma unroll
    for (int dt = 0; dt < 4; ++dt)
        #pragma unroll
        for (int r = 0; r < 4; ++r) {
            o_s[hd][irow[r]][dt * 16 + icol[r]]      = acc[dt][r];
            o_s[hd][16 + irow[r]][dt * 16 + icol[r]] = acc[4 + dt][r];
        }
    __syncthreads();

    {
        const int i  = tid >> 3;           // 0..31
        const int d8 = (tid & 7) * 8;      // 0..56
        float inv[NH];
        #pragma unroll
        for (int h = 0; h < NH; ++h) inv[h] = 0.25f / l_s[h][i];
        float4 s0 = {0.f, 0.f, 0.f, 0.f}, s1 = {0.f, 0.f, 0.f, 0.f};
        #pragma unroll
        for (int h = 0; h < NH; ++h) {
            const float4 v0 = *(const float4*)&o_s[h][i][d8];
            const float4 v1 = *(const float4*)&o_s[h][i][d8 + 4];
            s0.x += v0.x * inv[h]; s0.y += v0.y * inv[h];
            s0.z += v0.z * inv[h]; s0.w += v0.w * inv[h];
            s1.x += v1.x * inv[h]; s1.y += v1.y * inv[h];
            s1.z += v1.z * inv[h]; s1.w += v1.w * inv[h];
        }
        float* op = out + ((size_t)(b * NN + i0 + i)) * DD + d8;
        *(float4*)op = s0;
        *(float4*)(op + 4) = s1;
    }
}

extern "C" void kernel_launch(void* const* d_in, const int* in_sizes, int n_in,
                              void* d_out, int out_size, void* d_ws, size_t ws_size,
                              hipStream_t stream) {
    const float* x = nullptr; const int* adj = nullptr;
    const float* W = nullptr; const float* a = nullptr;
    for (int i = 0; i < n_in; ++i) {
        switch (in_sizes[i]) {
            case NB * NN * FIN:  x   = (const float*)d_in[i]; break;
            case NB * NN * NN:   adj = (const int*)d_in[i];   break;
            case FIN * 256:      W   = (const float*)d_in[i]; break;
            case 2 * DD:         a   = (const float*)d_in[i]; break;
            default: break;
        }
    }
    if (!x)   x   = (const float*)d_in[0];
    if (!adj) adj = (const int*)d_in[1];
    if (!W)   W   = (const float*)d_in[2];
    if (!a)   a   = (const float*)d_in[3];
    float* out = (float*)d_out;

    char* ws = (char*)d_ws;
    u16*   hTf = (u16*)(ws);
    float* ei  = (float*)(ws + 4194304);
    float* ej  = (float*)(ws + 4325376);

    k_gemm_h<<<dim3(64, NB), dim3(256), 0, stream>>>(x, W, a, hTf, ei, ej);
    k_attn<<<dim3(64, NB), dim3(256), 0, stream>>>(adj, hTf, ei, ej, out);
}

// Round 11
// 163.850 us; speedup vs baseline: 1.0603x; 1.0603x over previous
//
#include <hip/hip_runtime.h>

#define NN 2048
#define NH 4
#define DD 64
#define FIN 128
#define NB 4
#define LOG2E 1.44269504f

typedef unsigned short u16;
typedef unsigned int u32;
typedef short sh8 __attribute__((ext_vector_type(8)));
typedef float f32x4 __attribute__((ext_vector_type(4)));

static __device__ __forceinline__ u16 f2bf(float f) {   // RNE
    u32 u = __builtin_bit_cast(u32, f);
    u += 0x7fffu + ((u >> 16) & 1u);
    return (u16)(u >> 16);
}
static __device__ __forceinline__ u32 pk_bf(float a, float b) {
    u32 ua = __builtin_bit_cast(u32, a) + 0x8000u;
    u32 ub = __builtin_bit_cast(u32, b) + 0x8000u;
    return __builtin_amdgcn_perm(ub, ua, 0x07060302u);
}
static __device__ __forceinline__ float fast_exp2(float x) {
    float r;
    asm("v_exp_f32 %0, %1" : "=v"(r) : "v"(x));
    return r;
}

// ---- runtime C/D layout probe (load-bearing since R4) ----
static __device__ __forceinline__ void cd_probe(int ln15, int q, int* irow, int* icol) {
    sh8 pa, pb, qa, qb;
    #pragma unroll
    for (int ii = 0; ii < 8; ++ii) {
        pa[ii] = (short)f2bf((float)ln15);   // A[m][k] = m
        pb[ii] = 0;
        qa[ii] = 0;
        qb[ii] = (short)f2bf((float)ln15);   // B[k][n] = n
    }
    if (q == 0) { pb[0] = (short)f2bf(1.0f); qa[0] = (short)f2bf(1.0f); }
    f32x4 z = {};
    f32x4 prow = __builtin_amdgcn_mfma_f32_16x16x32_bf16(pa, pb, z, 0, 0, 0);
    f32x4 pcol = __builtin_amdgcn_mfma_f32_16x16x32_bf16(qa, qb, z, 0, 0, 0);
    #pragma unroll
    for (int r = 0; r < 4; ++r) {
        irow[r] = (int)(prow[r] + 0.5f);
        icol[r] = (int)(pcol[r] + 0.5f);
    }
}

// ws layout (bytes):
//   hTf  fragment-major  @ 0        : 4194304  ([b][hd][j32][dt4][lane64][8] bf16)
//   ei   [B][H][N] f32   @ 4194304  : 131072   (log2e-scaled)
//   ej   [B][H][N] f32   @ 4325376  : 131072   (log2e-scaled)
//   WT   [256][128] bf16 @ 4456448  : 65536
//   msk  [B][64][N] u32  @ 4521984  : 2097152

// blocks 0..2047: adj -> bitmask (int4/lane, nibble + shfl-OR). 2048..2079: W -> WT.
__global__ __launch_bounds__(256)
void k_pack(const int* __restrict__ adj, const float* __restrict__ W,
            u32* __restrict__ msk, u16* __restrict__ WT) {
    const int tid = threadIdx.x;
    if (blockIdx.x < 2048) {
        const int wid  = (blockIdx.x * 256 + tid) >> 6;   // 0..8191
        const int lane = tid & 63;
        for (int t = wid; t < NB * NN * 8; t += 8192) {
            const int c256 = t & 7;
            const int i    = (t >> 3) & (NN - 1);
            const int b    = t >> 14;
            const int4 v = *(const int4*)(adj + ((size_t)(b * NN + i)) * NN + c256 * 256 + lane * 4);
            u32 nib = (v.x ? 1u : 0u) | (v.y ? 2u : 0u) | (v.z ? 4u : 0u) | (v.w ? 8u : 0u);
            u32 w = nib << (4 * (lane & 7));
            w |= __shfl_xor(w, 1);
            w |= __shfl_xor(w, 2);
            w |= __shfl_xor(w, 4);
            if ((lane & 7) == 0)
                msk[((size_t)(b * 64 + c256 * 8 + (lane >> 3))) * NN + i] = w;
        }
    } else {
        const int bt  = blockIdx.x - 2048;   // 0..31
        const int kt  = bt & 3;
        const int ct8 = bt >> 2;
        __shared__ float tile[32][33];
        const int rr = tid >> 5, cc = tid & 31;
        #pragma unroll
        for (int i = 0; i < 4; ++i)
            tile[rr + 8 * i][cc] = W[(size_t)(kt * 32 + rr + 8 * i) * 256 + ct8 * 32 + cc];
        __syncthreads();
        #pragma unroll
        for (int i = 0; i < 4; ++i)
            WT[(size_t)(ct8 * 32 + rr + 8 * i) * FIN + kt * 32 + cc] = f2bf(tile[cc][rr + 8 * i]);
    }
}

// h = x@W in MFMA fragment-major layout + ei/ej (log2e-scaled). grid (nb=32, b=4), wave=head.
__global__ __launch_bounds__(256)
void k_gemm_h(const float* __restrict__ x, const u16* __restrict__ WT,
              const float* __restrict__ a,
              u16* __restrict__ hTf, float* __restrict__ ei_g, float* __restrict__ ej_g) {
    const int nb = blockIdx.x, b = blockIdx.y;
    const int tid = threadIdx.x, hd = tid >> 6, lane = tid & 63, ln15 = lane & 15, q = lane >> 4;
    const int q8 = q * 8;
    const int n0 = nb * 64;

    __shared__ u16 xs[64][136];
    __shared__ float cs[NH][4][16][20];
    {
        const int col = (tid & 31) * 4;
        const int r0  = tid >> 5;
        #pragma unroll
        for (int rr = 0; rr < 8; ++rr) {
            const int row = r0 + rr * 8;
            const float4 v = *(const float4*)(x + ((size_t)(b * NN + n0 + row)) * FIN + col);
            *(u32*)&xs[row][col]     = pk_bf(v.x, v.y);
            *(u32*)&xs[row][col + 2] = pk_bf(v.z, v.w);
        }
    }
    __syncthreads();

    int irow[4], icol[4];
    cd_probe(ln15, q, irow, icol);

    f32x4 acc[4][4] = {};                // [ct][nt]
    #pragma unroll
    for (int ks = 0; ks < 4; ++ks) {
        sh8 af[4], bfr[4];
        #pragma unroll
        for (int ct = 0; ct < 4; ++ct)
            af[ct] = *(const sh8*)(WT + (size_t)(hd * 64 + ct * 16 + ln15) * FIN + ks * 32 + q8);
        #pragma unroll
        for (int nt = 0; nt < 4; ++nt)
            bfr[nt] = *(const sh8*)&xs[nt * 16 + ln15][ks * 32 + q8];
        #pragma unroll
        for (int ct = 0; ct < 4; ++ct)
            #pragma unroll
            for (int nt = 0; nt < 4; ++nt)
                acc[ct][nt] = __builtin_amdgcn_mfma_f32_16x16x32_bf16(af[ct], bfr[nt], acc[ct][nt], 0, 0, 0);
    }

    float eip[4] = {}, ejq[4] = {};
    #pragma unroll
    for (int ct = 0; ct < 4; ++ct) {
        #pragma unroll
        for (int nt = 0; nt < 4; ++nt)
            #pragma unroll
            for (int r = 0; r < 4; ++r)
                cs[hd][nt][irow[r]][icol[r]] = acc[ct][nt][r];

        #pragma unroll
        for (int p = 0; p < 2; ++p) {
            const float4 c0 = *(const float4*)&cs[hd][2 * p + (q >> 1)][ln15][(q & 1) * 8];
            const float4 c1 = *(const float4*)&cs[hd][2 * p + (q >> 1)][ln15][(q & 1) * 8 + 4];
            uint4 o;
            o.x = pk_bf(c0.x, c0.y); o.y = pk_bf(c0.z, c0.w);
            o.z = pk_bf(c1.x, c1.y); o.w = pk_bf(c1.z, c1.w);
            *(uint4*)(hTf + ((((size_t)(b * NH + hd) * 64 + nb * 2 + p) * 4 + ct) * 512) + lane * 8) = o;
        }

        float a1v[4], a2v[4];
        #pragma unroll
        for (int r = 0; r < 4; ++r) {
            const int d = ct * 16 + 4 * q + r;
            a1v[r] = a[d] * LOG2E;
            a2v[r] = a[64 + d] * LOG2E;
        }
        #pragma unroll
        for (int nt = 0; nt < 4; ++nt)
            #pragma unroll
            for (int r = 0; r < 4; ++r) {
                const float v = cs[hd][nt][4 * q + r][ln15];
                eip[nt] += v * a1v[r];
                ejq[nt] += v * a2v[r];
            }
    }
    #pragma unroll
    for (int nt = 0; nt < 4; ++nt) {
        eip[nt] += __shfl_xor(eip[nt], 16);
        eip[nt] += __shfl_xor(eip[nt], 32);
        ejq[nt] += __shfl_xor(ejq[nt], 16);
        ejq[nt] += __shfl_xor(ejq[nt], 32);
    }
    if (lane < 16) {
        const size_t bhd = (size_t)(b * NH + hd) * NN;
        #pragma unroll
        for (int nt = 0; nt < 4; ++nt) {
            ei_g[bhd + n0 + nt * 16 + lane] = eip[nt];
            ej_g[bhd + n0 + nt * 16 + lane] = ejq[nt];
        }
    }
}

// Fused attention: grid (ib=128, b=4) = 512 blocks, block 256 (wave = head), i-tile 16,
// full j-range per block. msk/hTf L2-resident; direct out write; no partials.
__global__ __launch_bounds__(256, 2)
void k_attn(const u32* __restrict__ msk, const u16* __restrict__ hTf,
            const float* __restrict__ ei_g, const float* __restrict__ ej_g,
            float* __restrict__ out) {
    const int ib = blockIdx.x, b = blockIdx.y;
    const int tid = threadIdx.x, hd = tid >> 6, lane = tid & 63, ln15 = lane & 15, q = lane >> 4;
    const int q8 = q * 8;
    const int i0 = ib * 16;

    __shared__ float o_s[NH][16][68];
    __shared__ float l_s[NH][16];

    int irow[4], icol[4];
    cd_probe(ln15, q, irow, icol);

    const size_t bhd = (size_t)(b * NH + hd) * NN;
    const float eiv = ei_g[bhd + i0 + ln15];
    const u32*   mptr = msk + (size_t)(b * 64) * NN + i0 + ln15;   // + t*NN
    const float* ejp  = ej_g + bhd + q8;
    const u16*   hfp  = hTf + (size_t)(b * NH + hd) * (64 * 2048) + (size_t)lane * 8;

    sh8 ones;
    #pragma unroll
    for (int ii = 0; ii < 8; ++ii) ones[ii] = (short)0x3F80;

    f32x4 acc[4] = {};
    f32x4 accl = {};

    u32 m = mptr[0];
    float4 e0 = *(const float4*)(ejp);
    float4 e1 = *(const float4*)(ejp + 4);
    sh8 h0 = *(const sh8*)(hfp);
    sh8 h1 = *(const sh8*)(hfp + 512);
    sh8 h2 = *(const sh8*)(hfp + 1024);
    sh8 h3 = *(const sh8*)(hfp + 1536);

    for (int t = 0; t < 64; ++t) {
        const int tn = (t + 1) & 63;                      // wraps; last discarded
        const u32 mn = mptr[(size_t)tn * NN];
        const float4 e0n = *(const float4*)(ejp + tn * 32);
        const float4 e1n = *(const float4*)(ejp + tn * 32 + 4);
        const sh8 h0n = *(const sh8*)(hfp + (size_t)tn * 2048);
        const sh8 h1n = *(const sh8*)(hfp + (size_t)tn * 2048 + 512);
        const sh8 h2n = *(const sh8*)(hfp + (size_t)tn * 2048 + 1024);
        const sh8 h3n = *(const sh8*)(hfp + (size_t)tn * 2048 + 1536);

        const float ef[8] = { e0.x, e0.y, e0.z, e0.w, e1.x, e1.y, e1.z, e1.w };
        const u32 mq = m >> q8;
        float p[8];
        #pragma unroll
        for (int ii = 0; ii < 8; ++ii) {
            float e = eiv + ef[ii];
            e = fmaxf(e, 0.2f * e);
            const float ex = fast_exp2(e);
            p[ii] = (mq & (1u << ii)) ? ex : 0.f;
        }
        union { uint4 u; sh8 v; } av;
        av.u.x = pk_bf(p[0], p[1]); av.u.y = pk_bf(p[2], p[3]);
        av.u.z = pk_bf(p[4], p[5]); av.u.w = pk_bf(p[6], p[7]);

        acc[0] = __builtin_amdgcn_mfma_f32_16x16x32_bf16(av.v, h0, acc[0], 0, 0, 0);
        acc[1] = __builtin_amdgcn_mfma_f32_16x16x32_bf16(av.v, h1, acc[1], 0, 0, 0);
        acc[2] = __builtin_amdgcn_mfma_f32_16x16x32_bf16(av.v, h2, acc[2], 0, 0, 0);
        acc[3] = __builtin_amdgcn_mfma_f32_16x16x32_bf16(av.v, h3, acc[3], 0, 0, 0);
        accl   = __builtin_amdgcn_mfma_f32_16x16x32_bf16(av.v, ones, accl, 0, 0, 0);

        m = mn; e0 = e0n; e1 = e1n;
        h0 = h0n; h1 = h1n; h2 = h2n; h3 = h3n;
    }

    // epilogue: probe-mapped scatter to LDS, then normalize + head-mean
    #pragma unroll
    for (int r = 0; r < 4; ++r)
        l_s[hd][irow[r]] = accl[r];
    #pragma unroll
    for (int dt = 0; dt < 4; ++dt)
        #pragma unroll
        for (int r = 0; r < 4; ++r)
            o_s[hd][irow[r]][dt * 16 + icol[r]] = acc[dt][r];
    __syncthreads();

    {
        const int i  = tid >> 4;           // 0..15
        const int d4 = (tid & 15) * 4;     // 0..60
        float inv[NH];
        #pragma unroll
        for (int h = 0; h < NH; ++h) inv[h] = 0.25f / l_s[h][i];
        float4 s = {0.f, 0.f, 0.f, 0.f};
        #pragma unroll
        for (int h = 0; h < NH; ++h) {
            const float4 v = *(const float4*)&o_s[h][i][d4];
            s.x += v.x * inv[h]; s.y += v.y * inv[h];
            s.z += v.z * inv[h]; s.w += v.w * inv[h];
        }
        *(float4*)(out + ((size_t)(b * NN + i0 + i)) * DD + d4) = s;
    }
}

extern "C" void kernel_launch(void* const* d_in, const int* in_sizes, int n_in,
                              void* d_out, int out_size, void* d_ws, size_t ws_size,
                              hipStream_t stream) {
    const float* x = nullptr; const int* adj = nullptr;
    const float* W = nullptr; const float* a = nullptr;
    for (int i = 0; i < n_in; ++i) {
        switch (in_sizes[i]) {
            case NB * NN * FIN:  x   = (const float*)d_in[i]; break;
            case NB * NN * NN:   adj = (const int*)d_in[i];   break;
            case FIN * 256:      W   = (const float*)d_in[i]; break;
            case 2 * DD:         a   = (const float*)d_in[i]; break;
            default: break;
        }
    }
    if (!x)   x   = (const float*)d_in[0];
    if (!adj) adj = (const int*)d_in[1];
    if (!W)   W   = (const float*)d_in[2];
    if (!a)   a   = (const float*)d_in[3];
    float* out = (float*)d_out;

    char* ws = (char*)d_ws;
    u16*   hTf = (u16*)(ws);
    float* ei  = (float*)(ws + 4194304);
    float* ej  = (float*)(ws + 4325376);
    u16*   WT  = (u16*)(ws + 4456448);
    u32*   msk = (u32*)(ws + 4521984);

    k_pack<<<dim3(2080), dim3(256), 0, stream>>>(adj, W, msk, WT);
    k_gemm_h<<<dim3(32, NB), dim3(256), 0, stream>>>(x, WT, a, hTf, ei, ej);
    k_attn<<<dim3(128, NB), dim3(256), 0, stream>>>(msk, hTf, ei, ej, out);
}

// Round 12
// 147.764 us; speedup vs baseline: 1.1758x; 1.1089x over previous
//
#include <hip/hip_runtime.h>

#define NN 2048
#define NH 4
#define DD 64
#define FIN 128
#define NB 4
#define LOG2E 1.44269504f

typedef unsigned short u16;
typedef unsigned int u32;
typedef short sh8 __attribute__((ext_vector_type(8)));
typedef float f32x4 __attribute__((ext_vector_type(4)));

static __device__ __forceinline__ u16 f2bf(float f) {   // RNE
    u32 u = __builtin_bit_cast(u32, f);
    u += 0x7fffu + ((u >> 16) & 1u);
    return (u16)(u >> 16);
}
static __device__ __forceinline__ u32 pk_bf(float a, float b) {
    u32 ua = __builtin_bit_cast(u32, a) + 0x8000u;
    u32 ub = __builtin_bit_cast(u32, b) + 0x8000u;
    return __builtin_amdgcn_perm(ub, ua, 0x07060302u);
}
static __device__ __forceinline__ float fast_exp2(float x) {
    float r;
    asm("v_exp_f32 %0, %1" : "=v"(r) : "v"(x));
    return r;
}
// async global->LDS DMA, 16B/lane, LDS dst = uniform base + lane*16
static __device__ __forceinline__ void dma16(const u16* g, u16* l) {
    __builtin_amdgcn_global_load_lds((const __attribute__((address_space(1))) void*)g,
                                     (__attribute__((address_space(3))) void*)l, 16, 0, 0);
}

// ---- runtime C/D layout probe (load-bearing since R4) ----
static __device__ __forceinline__ void cd_probe(int ln15, int q, int* irow, int* icol) {
    sh8 pa, pb, qa, qb;
    #pragma unroll
    for (int ii = 0; ii < 8; ++ii) {
        pa[ii] = (short)f2bf((float)ln15);   // A[m][k] = m
        pb[ii] = 0;
        qa[ii] = 0;
        qb[ii] = (short)f2bf((float)ln15);   // B[k][n] = n
    }
    if (q == 0) { pb[0] = (short)f2bf(1.0f); qa[0] = (short)f2bf(1.0f); }
    f32x4 z = {};
    f32x4 prow = __builtin_amdgcn_mfma_f32_16x16x32_bf16(pa, pb, z, 0, 0, 0);
    f32x4 pcol = __builtin_amdgcn_mfma_f32_16x16x32_bf16(qa, qb, z, 0, 0, 0);
    #pragma unroll
    for (int r = 0; r < 4; ++r) {
        irow[r] = (int)(prow[r] + 0.5f);
        icol[r] = (int)(pcol[r] + 0.5f);
    }
}

// ws layout (bytes):
//   hTf  fragment-major  @ 0        : 4194304  ([b][hd][j32][dt4][lane64][8] bf16)
//   ei   [B][H][N] f32   @ 4194304  : 131072   (log2e-scaled)
//   ej   [B][H][N] f32   @ 4325376  : 131072   (log2e-scaled)
//   WT   [256][128] bf16 @ 4456448  : 65536
//   msk  [B][64][N] u32  @ 4521984  : 2097152

// blocks 0..2047: adj -> bitmask. 2048..2079: W -> WT.
__global__ __launch_bounds__(256)
void k_pack(const int* __restrict__ adj, const float* __restrict__ W,
            u32* __restrict__ msk, u16* __restrict__ WT) {
    const int tid = threadIdx.x;
    if (blockIdx.x < 2048) {
        const int wid  = (blockIdx.x * 256 + tid) >> 6;
        const int lane = tid & 63;
        for (int t = wid; t < NB * NN * 8; t += 8192) {
            const int c256 = t & 7;
            const int i    = (t >> 3) & (NN - 1);
            const int b    = t >> 14;
            const int4 v = *(const int4*)(adj + ((size_t)(b * NN + i)) * NN + c256 * 256 + lane * 4);
            u32 nib = (v.x ? 1u : 0u) | (v.y ? 2u : 0u) | (v.z ? 4u : 0u) | (v.w ? 8u : 0u);
            u32 w = nib << (4 * (lane & 7));
            w |= __shfl_xor(w, 1);
            w |= __shfl_xor(w, 2);
            w |= __shfl_xor(w, 4);
            if ((lane & 7) == 0)
                msk[((size_t)(b * 64 + c256 * 8 + (lane >> 3))) * NN + i] = w;
        }
    } else {
        const int bt  = blockIdx.x - 2048;
        const int kt  = bt & 3;
        const int ct8 = bt >> 2;
        __shared__ float tile[32][33];
        const int rr = tid >> 5, cc = tid & 31;
        #pragma unroll
        for (int i = 0; i < 4; ++i)
            tile[rr + 8 * i][cc] = W[(size_t)(kt * 32 + rr + 8 * i) * 256 + ct8 * 32 + cc];
        __syncthreads();
        #pragma unroll
        for (int i = 0; i < 4; ++i)
            WT[(size_t)(ct8 * 32 + rr + 8 * i) * FIN + kt * 32 + cc] = f2bf(tile[cc][rr + 8 * i]);
    }
}

// h = x@W in MFMA fragment-major layout + ei/ej (log2e-scaled). grid (nb=32, b=4), wave=head.
__global__ __launch_bounds__(256)
void k_gemm_h(const float* __restrict__ x, const u16* __restrict__ WT,
              const float* __restrict__ a,
              u16* __restrict__ hTf, float* __restrict__ ei_g, float* __restrict__ ej_g) {
    const int nb = blockIdx.x, b = blockIdx.y;
    const int tid = threadIdx.x, hd = tid >> 6, lane = tid & 63, ln15 = lane & 15, q = lane >> 4;
    const int q8 = q * 8;
    const int n0 = nb * 64;

    __shared__ u16 xs[64][136];
    __shared__ float cs[NH][4][16][20];
    {
        const int col = (tid & 31) * 4;
        const int r0  = tid >> 5;
        #pragma unroll
        for (int rr = 0; rr < 8; ++rr) {
            const int row = r0 + rr * 8;
            const float4 v = *(const float4*)(x + ((size_t)(b * NN + n0 + row)) * FIN + col);
            *(u32*)&xs[row][col]     = pk_bf(v.x, v.y);
            *(u32*)&xs[row][col + 2] = pk_bf(v.z, v.w);
        }
    }
    __syncthreads();

    int irow[4], icol[4];
    cd_probe(ln15, q, irow, icol);

    f32x4 acc[4][4] = {};
    #pragma unroll
    for (int ks = 0; ks < 4; ++ks) {
        sh8 af[4], bfr[4];
        #pragma unroll
        for (int ct = 0; ct < 4; ++ct)
            af[ct] = *(const sh8*)(WT + (size_t)(hd * 64 + ct * 16 + ln15) * FIN + ks * 32 + q8);
        #pragma unroll
        for (int nt = 0; nt < 4; ++nt)
            bfr[nt] = *(const sh8*)&xs[nt * 16 + ln15][ks * 32 + q8];
        #pragma unroll
        for (int ct = 0; ct < 4; ++ct)
            #pragma unroll
            for (int nt = 0; nt < 4; ++nt)
                acc[ct][nt] = __builtin_amdgcn_mfma_f32_16x16x32_bf16(af[ct], bfr[nt], acc[ct][nt], 0, 0, 0);
    }

    float eip[4] = {}, ejq[4] = {};
    #pragma unroll
    for (int ct = 0; ct < 4; ++ct) {
        #pragma unroll
        for (int nt = 0; nt < 4; ++nt)
            #pragma unroll
            for (int r = 0; r < 4; ++r)
                cs[hd][nt][irow[r]][icol[r]] = acc[ct][nt][r];

        #pragma unroll
        for (int p = 0; p < 2; ++p) {
            const float4 c0 = *(const float4*)&cs[hd][2 * p + (q >> 1)][ln15][(q & 1) * 8];
            const float4 c1 = *(const float4*)&cs[hd][2 * p + (q >> 1)][ln15][(q & 1) * 8 + 4];
            uint4 o;
            o.x = pk_bf(c0.x, c0.y); o.y = pk_bf(c0.z, c0.w);
            o.z = pk_bf(c1.x, c1.y); o.w = pk_bf(c1.z, c1.w);
            *(uint4*)(hTf + ((((size_t)(b * NH + hd) * 64 + nb * 2 + p) * 4 + ct) * 512) + lane * 8) = o;
        }

        float a1v[4], a2v[4];
        #pragma unroll
        for (int r = 0; r < 4; ++r) {
            const int d = ct * 16 + 4 * q + r;
            a1v[r] = a[d] * LOG2E;
            a2v[r] = a[64 + d] * LOG2E;
        }
        #pragma unroll
        for (int nt = 0; nt < 4; ++nt)
            #pragma unroll
            for (int r = 0; r < 4; ++r) {
                const float v = cs[hd][nt][4 * q + r][ln15];
                eip[nt] += v * a1v[r];
                ejq[nt] += v * a2v[r];
            }
    }
    #pragma unroll
    for (int nt = 0; nt < 4; ++nt) {
        eip[nt] += __shfl_xor(eip[nt], 16);
        eip[nt] += __shfl_xor(eip[nt], 32);
        ejq[nt] += __shfl_xor(ejq[nt], 16);
        ejq[nt] += __shfl_xor(ejq[nt], 32);
    }
    if (lane < 16) {
        const size_t bhd = (size_t)(b * NH + hd) * NN;
        #pragma unroll
        for (int nt = 0; nt < 4; ++nt) {
            ei_g[bhd + n0 + nt * 16 + lane] = eip[nt];
            ej_g[bhd + n0 + nt * 16 + lane] = ejq[nt];
        }
    }
}

// Fused attention, m97-style LDS-DMA double buffer.
// grid 256 blocks x 512 thr (8 waves): wave w -> (hd = w&3, ihalf = w>>2); i-tile 32.
// XCD swizzle: b from bid&7 so each XCD's L2 set is ~1.5 MB.
__global__ __launch_bounds__(512, 1)
void k_attn(const u32* __restrict__ msk, const u16* __restrict__ hTf,
            const float* __restrict__ ei_g, const float* __restrict__ ej_g,
            float* __restrict__ out) {
    const int bid = blockIdx.x;
    const int b   = (bid & 7) >> 1;
    const int ib  = ((bid >> 3) << 1) | (bid & 1);
    const int tid = threadIdx.x;
    const int w   = tid >> 6;
    const int hd  = w & 3;
    const int ih  = w >> 2;
    const int lane = tid & 63, ln15 = lane & 15, q = lane >> 4, q8 = q * 8;

    __shared__ __align__(16) u16 hbuf[2][NH][4][512];   // 32 KB: [buf][hd][dt][lane*8]
    __shared__ float ejs[NH][NN];                       // 32 KB (log2e-scaled f32)
    __shared__ u32   msk_s[64][32];                     // 8 KB
    __shared__ float o_s[NH][32][68];                   // 34.8 KB
    __shared__ float l_s[NH][32];

    // ---- prologue ----
    {   // msk slice: [j32][i] for i in [ib*32, +32)
        const int j32 = tid >> 3, ic = (tid & 7) * 4;
        const uint4 v = *(const uint4*)(msk + ((size_t)(b * 64 + j32)) * NN + ib * 32 + ic);
        *(uint4*)&msk_s[j32][ic] = v;
    }
    {   // ej rows, all heads, f32
        const int h = tid >> 7, off = (tid & 127) * 16;
        const float* src = ej_g + (size_t)(b * NH + h) * NN + off;
        #pragma unroll
        for (int k = 0; k < 4; ++k)
            *(float4*)&ejs[h][off + k * 4] = *(const float4*)(src + k * 4);
    }
    const u16* hfp = hTf + (size_t)(b * NH + hd) * (64 * 2048) + (size_t)lane * 8;
    if (ih == 0) {   // DMA tile 0
        #pragma unroll
        for (int dt = 0; dt < 4; ++dt)
            dma16(hfp + dt * 512, &hbuf[0][hd][dt][0]);
    }

    int irow[4], icol[4];
    cd_probe(ln15, q, irow, icol);

    const float eiv = ei_g[(size_t)(b * NH + hd) * NN + ib * 32 + ih * 16 + ln15];

    sh8 ones;
    #pragma unroll
    for (int ii = 0; ii < 8; ++ii) ones[ii] = (short)0x3F80;

    f32x4 acc[4] = {};
    f32x4 accl = {};

    __syncthreads();   // msk_s/ejs visible; tile-0 DMA drained

    for (int t = 0; t < 64; ++t) {
        const int cur = t & 1, nxt = cur ^ 1;
        if (ih == 0 && t < 63) {   // DMA next tile (drained at this iteration's barrier)
            const u16* g = hfp + (size_t)(t + 1) * 2048;
            #pragma unroll
            for (int dt = 0; dt < 4; ++dt)
                dma16(g + dt * 512, &hbuf[nxt][hd][dt][0]);
        }

        const u32 mq = msk_s[t][ih * 16 + ln15] >> q8;
        const float4 e0 = *(const float4*)&ejs[hd][t * 32 + q8];
        const float4 e1 = *(const float4*)&ejs[hd][t * 32 + q8 + 4];
        const sh8 h0 = *(const sh8*)&hbuf[cur][hd][0][lane * 8];
        const sh8 h1 = *(const sh8*)&hbuf[cur][hd][1][lane * 8];
        const sh8 h2 = *(const sh8*)&hbuf[cur][hd][2][lane * 8];
        const sh8 h3 = *(const sh8*)&hbuf[cur][hd][3][lane * 8];

        const float ef[8] = { e0.x, e0.y, e0.z, e0.w, e1.x, e1.y, e1.z, e1.w };
        float p[8];
        #pragma unroll
        for (int ii = 0; ii < 8; ++ii) {
            float e = eiv + ef[ii];
            e = fmaxf(e, 0.2f * e);
            const float ex = fast_exp2(e);
            p[ii] = (mq & (1u << ii)) ? ex : 0.f;
        }
        union { uint4 u; sh8 v; } av;
        av.u.x = pk_bf(p[0], p[1]); av.u.y = pk_bf(p[2], p[3]);
        av.u.z = pk_bf(p[4], p[5]); av.u.w = pk_bf(p[6], p[7]);

        acc[0] = __builtin_amdgcn_mfma_f32_16x16x32_bf16(av.v, h0, acc[0], 0, 0, 0);
        acc[1] = __builtin_amdgcn_mfma_f32_16x16x32_bf16(av.v, h1, acc[1], 0, 0, 0);
        acc[2] = __builtin_amdgcn_mfma_f32_16x16x32_bf16(av.v, h2, acc[2], 0, 0, 0);
        acc[3] = __builtin_amdgcn_mfma_f32_16x16x32_bf16(av.v, h3, acc[3], 0, 0, 0);
        accl   = __builtin_amdgcn_mfma_f32_16x16x32_bf16(av.v, ones, accl, 0, 0, 0);

        __syncthreads();   // drains DMA (vmcnt0) + protects buffer reuse
    }

    // ---- epilogue: probe-mapped scatter, normalize + head-mean ----
    #pragma unroll
    for (int r = 0; r < 4; ++r)
        l_s[hd][ih * 16 + irow[r]] = accl[r];
    #pragma unroll
    for (int dt = 0; dt < 4; ++dt)
        #pragma unroll
        for (int r = 0; r < 4; ++r)
            o_s[hd][ih * 16 + irow[r]][dt * 16 + icol[r]] = acc[dt][r];
    __syncthreads();

    {
        const int i  = tid >> 4;           // 0..31
        const int d4 = (tid & 15) * 4;
        float inv[NH];
        #pragma unroll
        for (int h = 0; h < NH; ++h) inv[h] = 0.25f / l_s[h][i];
        float4 s = {0.f, 0.f, 0.f, 0.f};
        #pragma unroll
        for (int h = 0; h < NH; ++h) {
            const float4 v = *(const float4*)&o_s[h][i][d4];
            s.x += v.x * inv[h]; s.y += v.y * inv[h];
            s.z += v.z * inv[h]; s.w += v.w * inv[h];
        }
        *(float4*)(out + ((size_t)(b * NN + ib * 32 + i)) * DD + d4) = s;
    }
}

extern "C" void kernel_launch(void* const* d_in, const int* in_sizes, int n_in,
                              void* d_out, int out_size, void* d_ws, size_t ws_size,
                              hipStream_t stream) {
    const float* x = nullptr; const int* adj = nullptr;
    const float* W = nullptr; const float* a = nullptr;
    for (int i = 0; i < n_in; ++i) {
        switch (in_sizes[i]) {
            case NB * NN * FIN:  x   = (const float*)d_in[i]; break;
            case NB * NN * NN:   adj = (const int*)d_in[i];   break;
            case FIN * 256:      W   = (const float*)d_in[i]; break;
            case 2 * DD:         a   = (const float*)d_in[i]; break;
            default: break;
        }
    }
    if (!x)   x   = (const float*)d_in[0];
    if (!adj) adj = (const int*)d_in[1];
    if (!W)   W   = (const float*)d_in[2];
    if (!a)   a   = (const float*)d_in[3];
    float* out = (float*)d_out;

    char* ws = (char*)d_ws;
    u16*   hTf = (u16*)(ws);
    float* ei  = (float*)(ws + 4194304);
    float* ej  = (float*)(ws + 4325376);
    u16*   WT  = (u16*)(ws + 4456448);
    u32*   msk = (u32*)(ws + 4521984);

    k_pack<<<dim3(2080), dim3(256), 0, stream>>>(adj, W, msk, WT);
    k_gemm_h<<<dim3(32, NB), dim3(256), 0, stream>>>(x, WT, a, hTf, ei, ej);
    k_attn<<<dim3(256), dim3(512), 0, stream>>>(msk, hTf, ei, ej, out);
}